// Round 11
// baseline (116.819 us; speedup 1.0000x reference)
//
#include <hip/hip_runtime.h>

// SymmetricContraction (MACE-style), B=128, C=128, E=10, L=16.
// Collapsed to GEMM + Q-fold:
//   D[m,p] = sum_kappa A[m,kappa] * Bm[kappa,p]
//     A1 = U3_1o as [768][528] ++ U2_1o cols -> [768][544] bf16 (ws)
//     A0 = U3_0e as [256][368] ++ U2_0e cols -> [256][384] bf16 (ws)
//     B[p][kappa]: 1o cols 0..543 = {x_i*z3_k | z2 | 0}, 0e cols 544..927
//   out[group,p] = sum_m Q[m,p]*D[m,p] + z1*U1-term,  Q = x[qa,p]*x[qb,p]
//
// Round 11: rounds 4-10 all bottlenecked on the in-kernel B build
// (stage->build->MFMA serial chain, MfmaUtil 7-14%). Now BOTH operands are
// precomputed bf16 in ws (A 1.03MB + B 30.4MB); main kernel is a pure
// streaming GEMM: 8x16B global loads + 16 MFMA per step, no LDS B, no
// barriers in the loop, no K tails (padding -> exactly 17/12 steps).
// Two-kernel ws handoff proven replay-safe by round 4. Fallback: round-3
// scalar kernel if ws too small.

typedef float  f32x4  __attribute__((ext_vector_type(4)));
typedef short  short8 __attribute__((ext_vector_type(8)));

namespace {
constexpr int EE = 10;
constexpr int LDA1 = 544;                 // 528 U3 + 6 U2 + 10 zero
constexpr int LDA0 = 384;                 // 368 U3 + 4 U2 + 12 zero
constexpr int A1_ELEMS = 768 * LDA1;      // 417792
constexpr int A0_ELEMS = 256 * LDA0;      // 98304
constexpr int A_ELEMS  = A1_ELEMS + A0_ELEMS;      // 516096 shorts
constexpr size_t WSA_BYTES = (size_t)A_ELEMS * 2;  // 1032192 (16B aligned)
constexpr int LDB = 928;                  // B row: 544 (1o) + 384 (0e) shorts
constexpr size_t WSB_BYTES = (size_t)16384 * LDB * 2;  // 30408704
constexpr size_t WS_NEED = WSA_BYTES + WSB_BYTES;
// zbuf row offsets (round-4 proven layout)
constexpr int Z31 = 0;   // 33
constexpr int Z21 = 33;  // 6
constexpr int Z11 = 39;  // 1
constexpr int Z30 = 40;  // 23
constexpr int Z20 = 63;  // 4
constexpr int Z10 = 67;  // 1
constexpr int NZ  = 68;

__device__ __forceinline__ unsigned short f2bf(float f) {
  union { float f; unsigned u; } v; v.f = f;
  unsigned r = v.u + 0x7FFFu + ((v.u >> 16) & 1u);
  return (unsigned short)(r >> 16);
}
}

__device__ __forceinline__ unsigned cvtpk(float lo, float hi) {
  unsigned r;
  asm("v_cvt_pk_bf16_f32 %0, %1, %2" : "=v"(r) : "v"(lo), "v"(hi));
  return r;
}

// ---- prep A: padded bf16 A into ws (round-4 proven) ----
__global__ __launch_bounds__(256) void prepA_kernel(
    const float* __restrict__ U3_1o, const float* __restrict__ U2_1o,
    const float* __restrict__ U3_0e, const float* __restrict__ U2_0e,
    unsigned short* __restrict__ wsA)
{
  int idx = blockIdx.x * 256 + threadIdx.x;
  if (idx < A1_ELEMS) {
    int m = idx / LDA1, k = idx - m * LDA1;
    float v = (k < 528) ? U3_1o[m * 528 + k]
            : (k < 534) ? U2_1o[m * 6 + (k - 528)] : 0.f;
    wsA[idx] = f2bf(v);
  } else if (idx < A_ELEMS) {
    int j = idx - A1_ELEMS;
    int m = j / LDA0, k = j - m * LDA0;
    float v = (k < 368) ? U3_0e[m * 368 + k]
            : (k < 372) ? U2_0e[m * 4 + (k - 368)] : 0.f;
    wsA[idx] = f2bf(v);
  }
}

// ---- prep B: B[p][kappa] bf16, 64 pairs per block ----
__global__ __launch_bounds__(256) void prepB_kernel(
    const float* __restrict__ x,      // [B][C][16]
    const float* __restrict__ y,      // [B][E]
    const float* __restrict__ w1_0e, const float* __restrict__ w2_0e,
    const float* __restrict__ w3_0e, const float* __restrict__ w1_1o,
    const float* __restrict__ w2_1o, const float* __restrict__ w3_1o,
    unsigned* __restrict__ wsBu)      // u32 view, row stride 464
{
  __shared__ float x_lds[16][64];
  __shared__ float zbuf[NZ][64];

  const int tid   = threadIdx.x;
  const int blk   = blockIdx.x;       // 0..255
  const int pair0 = blk * 64;
  const int b     = blk >> 1;

  for (int t = tid; t < 16 * 64; t += 256) {
    const int i = t >> 6, n = t & 63;
    x_lds[i][n] = x[(size_t)(pair0 + n) * 16 + i];
  }
  for (int t = tid; t < NZ * 64; t += 256) {
    const int n  = t & 63;
    const int zi = t >> 6;
    const int c  = ((blk & 1) << 6) + n;
    const float* yb = y + b * EE;
    const float* wsrc; int stride;
    if      (zi < Z21) { wsrc = w3_1o + (zi      ) * 128 + c; stride = 33 * 128; }
    else if (zi < Z11) { wsrc = w2_1o + (zi - Z21) * 128 + c; stride =  6 * 128; }
    else if (zi < Z30) { wsrc = w1_1o +                    c; stride =  1 * 128; }
    else if (zi < Z20) { wsrc = w3_0e + (zi - Z30) * 128 + c; stride = 23 * 128; }
    else if (zi < Z10) { wsrc = w2_0e + (zi - Z20) * 128 + c; stride =  4 * 128; }
    else               { wsrc = w1_0e +                    c; stride =  1 * 128; }
    float a = 0.f;
    #pragma unroll
    for (int e = 0; e < EE; ++e) a += wsrc[e * stride] * yb[e];
    zbuf[zi][n] = a;
  }
  __syncthreads();

  auto bval = [&](int col, int p) -> float {
    if (col < 544) {            // 1o part
      if (col < 528) { int i = col / 33, k = col - i * 33; return x_lds[i][p] * zbuf[Z31 + k][p]; }
      if (col < 534) return zbuf[Z21 + (col - 528)][p];
      return 0.f;
    } else {                    // 0e part
      int kk = col - 544;
      if (kk < 368) { int i = kk / 23, k = kk - i * 23; return x_lds[i][p] * zbuf[Z30 + k][p]; }
      if (kk < 372) return zbuf[Z20 + (kk - 368)][p];
      return 0.f;
    }
  };

  // coalesced writes: per p, threads cover the 464 u32 columns
  #pragma unroll 1
  for (int p = 0; p < 64; ++p) {
    unsigned* dst = wsBu + (size_t)(pair0 + p) * 464;
    #pragma unroll 1
    for (int colu = tid; colu < 464; colu += 256) {
      const int c0 = colu * 2;
      dst[colu] = cvtpk(bval(c0, p), bval(c0 + 1, p));
    }
  }
}

// ---- main: pure streaming GEMM + Q-fold ----
__global__ __launch_bounds__(512) void symcon_gemm(
    const float* __restrict__ x,      // [B][C][16]
    const float* __restrict__ y,      // [B][E]
    const float* __restrict__ U1_0e,  // [16]
    const float* __restrict__ U1_1o,  // [3][16]
    const float* __restrict__ w1_0e, const float* __restrict__ w1_1o,
    const unsigned short* __restrict__ wsA,
    const unsigned short* __restrict__ wsB,
    float* __restrict__ out)          // [B][512]
{
  __shared__ float x_lds[16][64];   // 4 KB
  __shared__ float red[8][64];      // 2 KB

  const int tid   = threadIdx.x;
  const int lane  = tid & 63;
  const int wv    = tid >> 6;          // 0..7
  const int lrow  = lane & 15;
  const int lgr   = lane >> 4;
  const int blk   = blockIdx.x;        // 0..511
  const int pgrp  = blk >> 1;          // 0..255
  const int half  = blk & 1;
  const int pair0 = pgrp * 64;
  const int b     = pgrp >> 1;

  for (int t = tid; t < 16 * 64; t += 512) {
    const int i = t >> 6, n = t & 63;
    x_lds[i][n] = x[(size_t)(pair0 + n) * 16 + i];
  }
  __syncthreads();

  // wave row assignment: half0 = 1o rows 0..511 (w0,w1); half1: wv<4 = 1o
  // rows 512..767 (w2), wv>=4 = 0e rows 0..255.
  const bool o1 = (half == 0) || (wv < 4);
  const int rbase   = o1 ? (half * 512 + wv * 64) : ((wv - 4) * 64);
  const int steps   = o1 ? 17 : 12;
  const int lda     = o1 ? LDA1 : LDA0;
  const int colbase = o1 ? 0 : 544;
  const unsigned short* Abase = o1 ? wsA : (wsA + A1_ELEMS);

  const unsigned short* aP[4];
  const unsigned short* bP[4];
  #pragma unroll
  for (int mf = 0; mf < 4; ++mf)
    aP[mf] = Abase + (size_t)(rbase + mf * 16 + lrow) * lda + lgr * 8;
  #pragma unroll
  for (int nf = 0; nf < 4; ++nf)
    bP[nf] = wsB + (size_t)(pair0 + nf * 16 + lrow) * LDB + colbase + lgr * 8;

  f32x4 acc[4][4] = {};

  #pragma unroll 1
  for (int t = 0; t < steps; ++t) {
    short8 af[4], bf[4];
    #pragma unroll
    for (int mf = 0; mf < 4; ++mf) af[mf] = *(const short8*)(aP[mf] + t * 32);
    #pragma unroll
    for (int nf = 0; nf < 4; ++nf) bf[nf] = *(const short8*)(bP[nf] + t * 32);
    #pragma unroll
    for (int mf = 0; mf < 4; ++mf)
      #pragma unroll
      for (int nf = 0; nf < 4; ++nf)
        acc[mf][nf] = __builtin_amdgcn_mfma_f32_16x16x32_bf16(af[mf], bf[nf], acc[mf][nf], 0, 0, 0);
  }

  // ---- Q-fold + in-wave reduce ----
  float s[4] = {0.f, 0.f, 0.f, 0.f};
  const int rg = lgr * 4;
  #pragma unroll
  for (int mf = 0; mf < 4; ++mf) {
    #pragma unroll
    for (int reg = 0; reg < 4; ++reg) {
      const int q  = (rbase + mf * 16 + rg + reg) & 255;
      const int qa = q >> 4, qb = q & 15;
      #pragma unroll
      for (int nf = 0; nf < 4; ++nf) {
        const int p = nf * 16 + lrow;
        s[nf] += acc[mf][nf][reg] * (x_lds[qa][p] * x_lds[qb][p]);
      }
    }
  }
  #pragma unroll
  for (int nf = 0; nf < 4; ++nf) {
    s[nf] += __shfl_xor(s[nf], 16);
    s[nf] += __shfl_xor(s[nf], 32);
  }
  if (lane < 16) {
    #pragma unroll
    for (int nf = 0; nf < 4; ++nf) red[wv][nf * 16 + lane] = s[nf];
  }
  __syncthreads();

  // ---- combine + U1 terms + store (2 output groups per block) ----
  if (tid < 128) {
    const int slot = tid >> 6;   // 0 or 1
    const int n    = tid & 63;
    const int cc   = ((pgrp & 1) << 6) + n;
    float v = red[4 * slot][n] + red[4 * slot + 1][n]
            + red[4 * slot + 2][n] + red[4 * slot + 3][n];
    if (half == 0 || slot == 0) {
      const int w = (half == 0) ? slot : 2;
      float u1 = 0.f, z1 = 0.f;
      #pragma unroll
      for (int xx = 0; xx < 16; ++xx) u1 += U1_1o[w * 16 + xx] * x_lds[xx][n];
      #pragma unroll
      for (int e = 0; e < EE; ++e) z1 += w1_1o[e * 128 + cc] * y[b * EE + e];
      out[(size_t)b * 512 + 128 + cc * 3 + w] = v + z1 * u1;
    } else {
      float u1 = 0.f, z1 = 0.f;
      #pragma unroll
      for (int xx = 0; xx < 16; ++xx) u1 += U1_0e[xx] * x_lds[xx][n];
      #pragma unroll
      for (int e = 0; e < EE; ++e) z1 += w1_0e[e * 128 + cc] * y[b * EE + e];
      out[(size_t)b * 512 + cc] = v + z1 * u1;
    }
  }
}

// ---- fallback: round-3 scalar kernel (proven), used if ws too small ----
__global__ __launch_bounds__(512, 2) void symcon_fallback(
    const float* __restrict__ x, const float* __restrict__ y,
    const float* __restrict__ U1_0e, const float* __restrict__ U2_0e,
    const float* __restrict__ U3_0e, const float* __restrict__ U1_1o,
    const float* __restrict__ U2_1o, const float* __restrict__ U3_1o,
    const float* __restrict__ w1_0e, const float* __restrict__ w2_0e,
    const float* __restrict__ w3_0e, const float* __restrict__ w1_1o,
    const float* __restrict__ w2_1o, const float* __restrict__ w3_1o,
    float* __restrict__ out)
{
  __shared__ float x_lds[16][64];
  __shared__ float red[8][64];
  const int tid  = threadIdx.x;
  const int lane = tid & 63;
  const int wv   = __builtin_amdgcn_readfirstlane(tid >> 6);
  const int blk  = blockIdx.x;
  const int pair0 = blk * 64;
  const int b    = blk >> 1;
  const int c    = ((blk & 1) << 6) + lane;

  for (int t = tid; t < 16 * 64; t += 512) {
    const int i = t >> 6, n = t & 63;
    x_lds[i][n] = x[(size_t)(pair0 + n) * 16 + i];
  }
  __syncthreads();

  float yv[EE];
  #pragma unroll
  for (int e = 0; e < EE; ++e) yv[e] = y[b * EE + e];

  const int grp  = wv >> 1;
  const int half = wv & 1;
  const int q00  = half * 128;
  float s = 0.f;

  if (grp < 3) {
    float z3[33];
    #pragma unroll
    for (int k = 0; k < 33; ++k) {
      float a = 0.f;
      #pragma unroll
      for (int e = 0; e < EE; ++e) a += w3_1o[(e * 33 + k) * 128 + c] * yv[e];
      z3[k] = a;
    }
    float z2[6];
    #pragma unroll
    for (int k = 0; k < 6; ++k) {
      float a = 0.f;
      #pragma unroll
      for (int e = 0; e < EE; ++e) a += w2_1o[(e * 6 + k) * 128 + c] * yv[e];
      z2[k] = a;
    }
    const float* __restrict__ U3base = U3_1o + ((size_t)grp * 256 + q00) * 528;
    const float* __restrict__ U2base = U2_1o + (grp * 256 + q00) * 6;
    #pragma unroll 1
    for (int rb = 0; rb < 16; ++rb) {
      float acc[8];
      #pragma unroll
      for (int r = 0; r < 8; ++r) acc[r] = 0.f;
      #pragma unroll 2
      for (int i = 0; i < 16; ++i) {
        const float xi = x_lds[i][lane];
        float pj[33];
        #pragma unroll
        for (int k = 0; k < 33; ++k) pj[k] = xi * z3[k];
        const float* __restrict__ Ur = U3base + (size_t)(rb * 8) * 528 + i * 33;
        #pragma unroll
        for (int r = 0; r < 8; ++r)
          #pragma unroll
          for (int k = 0; k < 33; ++k) acc[r] += Ur[r * 528 + k] * pj[k];
      }
      #pragma unroll
      for (int r = 0; r < 8; ++r) {
        const int q = q00 + rb * 8 + r;
        float a2 = acc[r];
        #pragma unroll
        for (int k = 0; k < 6; ++k) a2 += U2base[(rb * 8 + r) * 6 + k] * z2[k];
        s += a2 * (x_lds[q >> 4][lane] * x_lds[q & 15][lane]);
      }
    }
  } else {
    float z3[23];
    #pragma unroll
    for (int k = 0; k < 23; ++k) {
      float a = 0.f;
      #pragma unroll
      for (int e = 0; e < EE; ++e) a += w3_0e[(e * 23 + k) * 128 + c] * yv[e];
      z3[k] = a;
    }
    float z2[4];
    #pragma unroll
    for (int k = 0; k < 4; ++k) {
      float a = 0.f;
      #pragma unroll
      for (int e = 0; e < EE; ++e) a += w2_0e[(e * 4 + k) * 128 + c] * yv[e];
      z2[k] = a;
    }
    const float* __restrict__ U3base = U3_0e + (size_t)q00 * 368;
    const float* __restrict__ U2base = U2_0e + q00 * 4;
    #pragma unroll 1
    for (int rb = 0; rb < 16; ++rb) {
      float acc[8];
      #pragma unroll
      for (int r = 0; r < 8; ++r) acc[r] = 0.f;
      #pragma unroll 2
      for (int i = 0; i < 16; ++i) {
        const float xi = x_lds[i][lane];
        float pj[23];
        #pragma unroll
        for (int k = 0; k < 23; ++k) pj[k] = xi * z3[k];
        const float* __restrict__ Ur = U3base + (size_t)(rb * 8) * 368 + i * 23;
        #pragma unroll
        for (int r = 0; r < 8; ++r)
          #pragma unroll
          for (int k = 0; k < 23; ++k) acc[r] += Ur[r * 368 + k] * pj[k];
      }
      #pragma unroll
      for (int r = 0; r < 8; ++r) {
        const int q = q00 + rb * 8 + r;
        float a2 = acc[r];
        #pragma unroll
        for (int k = 0; k < 4; ++k) a2 += U2base[(rb * 8 + r) * 4 + k] * z2[k];
        s += a2 * (x_lds[q >> 4][lane] * x_lds[q & 15][lane]);
      }
    }
  }

  red[wv][lane] = s;
  __syncthreads();

  if (tid < 256) {
    const int slot = tid >> 6;
    const int n    = tid & 63;
    const int cc   = ((blk & 1) << 6) + n;
    float u1 = 0.f, z1 = 0.f;
    if (slot < 3) {
      #pragma unroll
      for (int xx = 0; xx < 16; ++xx) u1 += U1_1o[slot * 16 + xx] * x_lds[xx][n];
      #pragma unroll
      for (int e = 0; e < EE; ++e) z1 += w1_1o[e * 128 + cc] * y[b * EE + e];
      out[(size_t)b * 512 + 128 + cc * 3 + slot] = red[2 * slot][n] + red[2 * slot + 1][n] + z1 * u1;
    } else {
      #pragma unroll
      for (int xx = 0; xx < 16; ++xx) u1 += U1_0e[xx] * x_lds[xx][n];
      #pragma unroll
      for (int e = 0; e < EE; ++e) z1 += w1_0e[e * 128 + cc] * y[b * EE + e];
      out[(size_t)b * 512 + cc] = red[6][n] + red[7][n] + z1 * u1;
    }
  }
}

extern "C" void kernel_launch(void* const* d_in, const int* in_sizes, int n_in,
                              void* d_out, int out_size, void* d_ws, size_t ws_size,
                              hipStream_t stream) {
  const float* x     = (const float*)d_in[0];
  const float* y     = (const float*)d_in[1];
  const float* U1_0e = (const float*)d_in[2];
  const float* U2_0e = (const float*)d_in[3];
  const float* U3_0e = (const float*)d_in[4];
  const float* U1_1o = (const float*)d_in[5];
  const float* U2_1o = (const float*)d_in[6];
  const float* U3_1o = (const float*)d_in[7];
  const float* w1_0e = (const float*)d_in[8];
  const float* w2_0e = (const float*)d_in[9];
  const float* w3_0e = (const float*)d_in[10];
  const float* w1_1o = (const float*)d_in[11];
  const float* w2_1o = (const float*)d_in[12];
  const float* w3_1o = (const float*)d_in[13];
  (void)in_sizes; (void)n_in; (void)out_size;

  if (ws_size >= WS_NEED) {
    unsigned short* wsA = (unsigned short*)d_ws;
    unsigned short* wsB = (unsigned short*)((char*)d_ws + WSA_BYTES);
    hipLaunchKernelGGL(prepA_kernel, dim3((A_ELEMS + 255) / 256), dim3(256), 0, stream,
                       U3_1o, U2_1o, U3_0e, U2_0e, wsA);
    hipLaunchKernelGGL(prepB_kernel, dim3(256), dim3(256), 0, stream,
                       x, y, w1_0e, w2_0e, w3_0e, w1_1o, w2_1o, w3_1o,
                       (unsigned*)wsB);
    hipLaunchKernelGGL(symcon_gemm, dim3(512), dim3(512), 0, stream,
                       x, y, U1_0e, U1_1o, w1_0e, w1_1o,
                       wsA, wsB, (float*)d_out);
  } else {
    hipLaunchKernelGGL(symcon_fallback, dim3(256), dim3(512), 0, stream,
                       x, y, U1_0e, U2_0e, U3_0e, U1_1o, U2_1o, U3_1o,
                       w1_0e, w2_0e, w3_0e, w1_1o, w2_1o, w3_1o,
                       (float*)d_out);
  }
}

// Round 12
// 91.055 us; speedup vs baseline: 1.2829x; 1.2829x over previous
//
#include <hip/hip_runtime.h>

// SymmetricContraction (MACE-style), B=128, C=128, E=10, L=16.
// Collapsed to GEMM + Q-fold:
//   D[m,p] = sum_kappa A[m,kappa] * Bm[kappa,p]
//     A1 = U3_1o as [768][528] ++ U2_1o cols -> [768][544] bf16 (ws)
//     A0 = U3_0e as [256][368] ++ U2_0e cols -> [256][384] bf16 (ws)
//     B[p][kappa]: 1o cols 0..543 = {x_i*z3_k | z2 | 0}, 0e cols 544..927
//   out[group,p] = sum_m Q[m,p]*D[m,p] + z1*U1-term,  Q = x[qa,p]*x[qb,p]
//
// Round 12: round 11's prepB was 69us (60% of total) -- 256 blocks, serial
// 64-pair loop. Now ONE PAIR PER BLOCK (16384 blocks): 84 threads stage
// x/z to LDS, 256 threads write 464 u32 coalesced. prepA merged into the
// same launch (blocks >= 16384). GEMM unchanged except grid remap
// (pgrp=blk&255, half=blk>>8) so the 2 blocks sharing a B slice are on the
// same XCD (delta=256 = 0 mod 8) -> B re-reads hit local L2.

typedef float  f32x4  __attribute__((ext_vector_type(4)));
typedef short  short8 __attribute__((ext_vector_type(8)));

namespace {
constexpr int EE = 10;
constexpr int LDA1 = 544;                 // 528 U3 + 6 U2 + 10 zero
constexpr int LDA0 = 384;                 // 368 U3 + 4 U2 + 12 zero
constexpr int A1_ELEMS = 768 * LDA1;      // 417792
constexpr int A0_ELEMS = 256 * LDA0;      // 98304
constexpr int A_ELEMS  = A1_ELEMS + A0_ELEMS;      // 516096 shorts
constexpr size_t WSA_BYTES = (size_t)A_ELEMS * 2;  // 1032192 (16B aligned)
constexpr int LDB = 928;                  // B row: 544 (1o) + 384 (0e) shorts
constexpr size_t WSB_BYTES = (size_t)16384 * LDB * 2;  // 30408704
constexpr size_t WS_NEED = WSA_BYTES + WSB_BYTES;
constexpr int NB_B = 16384;                       // prep blocks for B
constexpr int NB_A = (A_ELEMS + 255) / 256;       // 2016 prep blocks for A
// z row offsets
constexpr int Z31 = 0;   // 33
constexpr int Z21 = 33;  // 6
constexpr int Z11 = 39;  // 1
constexpr int Z30 = 40;  // 23
constexpr int Z20 = 63;  // 4
constexpr int Z10 = 67;  // 1
constexpr int NZ  = 68;

__device__ __forceinline__ unsigned short f2bf(float f) {
  union { float f; unsigned u; } v; v.f = f;
  unsigned r = v.u + 0x7FFFu + ((v.u >> 16) & 1u);
  return (unsigned short)(r >> 16);
}
}

__device__ __forceinline__ unsigned cvtpk(float lo, float hi) {
  unsigned r;
  asm("v_cvt_pk_bf16_f32 %0, %1, %2" : "=v"(r) : "v"(lo), "v"(hi));
  return r;
}

// ---- prep: blocks < NB_B build B (one pair each); rest copy A ----
__global__ __launch_bounds__(256) void prep_kernel(
    const float* __restrict__ x,      // [B][C][16]
    const float* __restrict__ y,      // [B][E]
    const float* __restrict__ U3_1o, const float* __restrict__ U2_1o,
    const float* __restrict__ U3_0e, const float* __restrict__ U2_0e,
    const float* __restrict__ w1_0e, const float* __restrict__ w2_0e,
    const float* __restrict__ w3_0e, const float* __restrict__ w1_1o,
    const float* __restrict__ w2_1o, const float* __restrict__ w3_1o,
    unsigned short* __restrict__ wsA,
    unsigned* __restrict__ wsBu)      // u32 view, row stride 464
{
  const int blk = blockIdx.x;
  const int tid = threadIdx.x;

  if (blk >= NB_B) {
    // ---- A copy: padded bf16 ----
    const int idx = (blk - NB_B) * 256 + tid;
    if (idx < A1_ELEMS) {
      int m = idx / LDA1, k = idx - m * LDA1;
      float v = (k < 528) ? U3_1o[m * 528 + k]
              : (k < 534) ? U2_1o[m * 6 + (k - 528)] : 0.f;
      wsA[idx] = f2bf(v);
    } else if (idx < A_ELEMS) {
      int j = idx - A1_ELEMS;
      int m = j / LDA0, k = j - m * LDA0;
      float v = (k < 368) ? U3_0e[m * 368 + k]
              : (k < 372) ? U2_0e[m * 4 + (k - 368)] : 0.f;
      wsA[idx] = f2bf(v);
    }
    return;
  }

  // ---- B build: one pair p per block ----
  __shared__ float xs[16];
  __shared__ float zs[NZ];

  const int p = blk;
  const int b = p >> 7;
  const int c = p & 127;

  if (tid < 16) {
    xs[tid] = x[(size_t)p * 16 + tid];
  } else if (tid < 16 + NZ) {
    const int zi = tid - 16;
    const float* yb = y + b * EE;
    const float* wsrc; int stride;
    if      (zi < Z21) { wsrc = w3_1o + (zi      ) * 128 + c; stride = 33 * 128; }
    else if (zi < Z11) { wsrc = w2_1o + (zi - Z21) * 128 + c; stride =  6 * 128; }
    else if (zi < Z30) { wsrc = w1_1o +                    c; stride =  1 * 128; }
    else if (zi < Z20) { wsrc = w3_0e + (zi - Z30) * 128 + c; stride = 23 * 128; }
    else if (zi < Z10) { wsrc = w2_0e + (zi - Z20) * 128 + c; stride =  4 * 128; }
    else               { wsrc = w1_0e +                    c; stride =  1 * 128; }
    float a = 0.f;
    #pragma unroll
    for (int e = 0; e < EE; ++e) a += wsrc[e * stride] * yb[e];
    zs[zi] = a;
  }
  __syncthreads();

  auto bval = [&](int col) -> float {
    if (col < 544) {            // 1o part
      if (col < 528) { int i = col / 33, k = col - i * 33; return xs[i] * zs[Z31 + k]; }
      if (col < 534) return zs[Z21 + (col - 528)];
      return 0.f;
    } else {                    // 0e part
      int kk = col - 544;
      if (kk < 368) { int i = kk / 23, k = kk - i * 23; return xs[i] * zs[Z30 + k]; }
      if (kk < 372) return zs[Z20 + (kk - 368)];
      return 0.f;
    }
  };

  unsigned* dst = wsBu + (size_t)p * 464;
  #pragma unroll
  for (int pass = 0; pass < 2; ++pass) {
    const int colu = tid + pass * 256;
    if (colu < 464) {
      const int c0 = colu * 2;
      dst[colu] = cvtpk(bval(c0), bval(c0 + 1));
    }
  }
}

// ---- main: pure streaming GEMM + Q-fold ----
__global__ __launch_bounds__(512) void symcon_gemm(
    const float* __restrict__ x,      // [B][C][16]
    const float* __restrict__ y,      // [B][E]
    const float* __restrict__ U1_0e,  // [16]
    const float* __restrict__ U1_1o,  // [3][16]
    const float* __restrict__ w1_0e, const float* __restrict__ w1_1o,
    const unsigned short* __restrict__ wsA,
    const unsigned short* __restrict__ wsB,
    float* __restrict__ out)          // [B][512]
{
  __shared__ float x_lds[16][64];   // 4 KB
  __shared__ float red[8][64];      // 2 KB

  const int tid   = threadIdx.x;
  const int lane  = tid & 63;
  const int wv    = tid >> 6;          // 0..7
  const int lrow  = lane & 15;
  const int lgr   = lane >> 4;
  const int blk   = blockIdx.x;        // 0..511
  const int pgrp  = blk & 255;         // same-B blocks are blk, blk+256 -> same XCD
  const int half  = blk >> 8;
  const int pair0 = pgrp * 64;
  const int b     = pgrp >> 1;

  for (int t = tid; t < 16 * 64; t += 512) {
    const int i = t >> 6, n = t & 63;
    x_lds[i][n] = x[(size_t)(pair0 + n) * 16 + i];
  }
  __syncthreads();

  // wave row assignment: half0 = 1o rows 0..511 (w0,w1); half1: wv<4 = 1o
  // rows 512..767 (w2), wv>=4 = 0e rows 0..255.
  const bool o1 = (half == 0) || (wv < 4);
  const int rbase   = o1 ? (half * 512 + wv * 64) : ((wv - 4) * 64);
  const int steps   = o1 ? 17 : 12;
  const int lda     = o1 ? LDA1 : LDA0;
  const int colbase = o1 ? 0 : 544;
  const unsigned short* Abase = o1 ? wsA : (wsA + A1_ELEMS);

  const unsigned short* aP[4];
  const unsigned short* bP[4];
  #pragma unroll
  for (int mf = 0; mf < 4; ++mf)
    aP[mf] = Abase + (size_t)(rbase + mf * 16 + lrow) * lda + lgr * 8;
  #pragma unroll
  for (int nf = 0; nf < 4; ++nf)
    bP[nf] = wsB + (size_t)(pair0 + nf * 16 + lrow) * LDB + colbase + lgr * 8;

  f32x4 acc[4][4] = {};

  #pragma unroll 1
  for (int t = 0; t < steps; ++t) {
    short8 af[4], bf[4];
    #pragma unroll
    for (int mf = 0; mf < 4; ++mf) af[mf] = *(const short8*)(aP[mf] + t * 32);
    #pragma unroll
    for (int nf = 0; nf < 4; ++nf) bf[nf] = *(const short8*)(bP[nf] + t * 32);
    #pragma unroll
    for (int mf = 0; mf < 4; ++mf)
      #pragma unroll
      for (int nf = 0; nf < 4; ++nf)
        acc[mf][nf] = __builtin_amdgcn_mfma_f32_16x16x32_bf16(af[mf], bf[nf], acc[mf][nf], 0, 0, 0);
  }

  // ---- Q-fold + in-wave reduce ----
  float s[4] = {0.f, 0.f, 0.f, 0.f};
  const int rg = lgr * 4;
  #pragma unroll
  for (int mf = 0; mf < 4; ++mf) {
    #pragma unroll
    for (int reg = 0; reg < 4; ++reg) {
      const int q  = (rbase + mf * 16 + rg + reg) & 255;
      const int qa = q >> 4, qb = q & 15;
      #pragma unroll
      for (int nf = 0; nf < 4; ++nf) {
        const int p = nf * 16 + lrow;
        s[nf] += acc[mf][nf][reg] * (x_lds[qa][p] * x_lds[qb][p]);
      }
    }
  }
  #pragma unroll
  for (int nf = 0; nf < 4; ++nf) {
    s[nf] += __shfl_xor(s[nf], 16);
    s[nf] += __shfl_xor(s[nf], 32);
  }
  if (lane < 16) {
    #pragma unroll
    for (int nf = 0; nf < 4; ++nf) red[wv][nf * 16 + lane] = s[nf];
  }
  __syncthreads();

  // ---- combine + U1 terms + store (2 output groups per block) ----
  if (tid < 128) {
    const int slot = tid >> 6;   // 0 or 1
    const int n    = tid & 63;
    const int cc   = ((pgrp & 1) << 6) + n;
    float v = red[4 * slot][n] + red[4 * slot + 1][n]
            + red[4 * slot + 2][n] + red[4 * slot + 3][n];
    if (half == 0 || slot == 0) {
      const int w = (half == 0) ? slot : 2;
      float u1 = 0.f, z1 = 0.f;
      #pragma unroll
      for (int xx = 0; xx < 16; ++xx) u1 += U1_1o[w * 16 + xx] * x_lds[xx][n];
      #pragma unroll
      for (int e = 0; e < EE; ++e) z1 += w1_1o[e * 128 + cc] * y[b * EE + e];
      out[(size_t)b * 512 + 128 + cc * 3 + w] = v + z1 * u1;
    } else {
      float u1 = 0.f, z1 = 0.f;
      #pragma unroll
      for (int xx = 0; xx < 16; ++xx) u1 += U1_0e[xx] * x_lds[xx][n];
      #pragma unroll
      for (int e = 0; e < EE; ++e) z1 += w1_0e[e * 128 + cc] * y[b * EE + e];
      out[(size_t)b * 512 + cc] = v + z1 * u1;
    }
  }
}

// ---- fallback: round-3 scalar kernel (proven), used if ws too small ----
__global__ __launch_bounds__(512, 2) void symcon_fallback(
    const float* __restrict__ x, const float* __restrict__ y,
    const float* __restrict__ U1_0e, const float* __restrict__ U2_0e,
    const float* __restrict__ U3_0e, const float* __restrict__ U1_1o,
    const float* __restrict__ U2_1o, const float* __restrict__ U3_1o,
    const float* __restrict__ w1_0e, const float* __restrict__ w2_0e,
    const float* __restrict__ w3_0e, const float* __restrict__ w1_1o,
    const float* __restrict__ w2_1o, const float* __restrict__ w3_1o,
    float* __restrict__ out)
{
  __shared__ float x_lds[16][64];
  __shared__ float red[8][64];
  const int tid  = threadIdx.x;
  const int lane = tid & 63;
  const int wv   = __builtin_amdgcn_readfirstlane(tid >> 6);
  const int blk  = blockIdx.x;
  const int pair0 = blk * 64;
  const int b    = blk >> 1;
  const int c    = ((blk & 1) << 6) + lane;

  for (int t = tid; t < 16 * 64; t += 512) {
    const int i = t >> 6, n = t & 63;
    x_lds[i][n] = x[(size_t)(pair0 + n) * 16 + i];
  }
  __syncthreads();

  float yv[EE];
  #pragma unroll
  for (int e = 0; e < EE; ++e) yv[e] = y[b * EE + e];

  const int grp  = wv >> 1;
  const int half = wv & 1;
  const int q00  = half * 128;
  float s = 0.f;

  if (grp < 3) {
    float z3[33];
    #pragma unroll
    for (int k = 0; k < 33; ++k) {
      float a = 0.f;
      #pragma unroll
      for (int e = 0; e < EE; ++e) a += w3_1o[(e * 33 + k) * 128 + c] * yv[e];
      z3[k] = a;
    }
    float z2[6];
    #pragma unroll
    for (int k = 0; k < 6; ++k) {
      float a = 0.f;
      #pragma unroll
      for (int e = 0; e < EE; ++e) a += w2_1o[(e * 6 + k) * 128 + c] * yv[e];
      z2[k] = a;
    }
    const float* __restrict__ U3base = U3_1o + ((size_t)grp * 256 + q00) * 528;
    const float* __restrict__ U2base = U2_1o + (grp * 256 + q00) * 6;
    #pragma unroll 1
    for (int rb = 0; rb < 16; ++rb) {
      float acc[8];
      #pragma unroll
      for (int r = 0; r < 8; ++r) acc[r] = 0.f;
      #pragma unroll 2
      for (int i = 0; i < 16; ++i) {
        const float xi = x_lds[i][lane];
        float pj[33];
        #pragma unroll
        for (int k = 0; k < 33; ++k) pj[k] = xi * z3[k];
        const float* __restrict__ Ur = U3base + (size_t)(rb * 8) * 528 + i * 33;
        #pragma unroll
        for (int r = 0; r < 8; ++r)
          #pragma unroll
          for (int k = 0; k < 33; ++k) acc[r] += Ur[r * 528 + k] * pj[k];
      }
      #pragma unroll
      for (int r = 0; r < 8; ++r) {
        const int q = q00 + rb * 8 + r;
        float a2 = acc[r];
        #pragma unroll
        for (int k = 0; k < 6; ++k) a2 += U2base[(rb * 8 + r) * 6 + k] * z2[k];
        s += a2 * (x_lds[q >> 4][lane] * x_lds[q & 15][lane]);
      }
    }
  } else {
    float z3[23];
    #pragma unroll
    for (int k = 0; k < 23; ++k) {
      float a = 0.f;
      #pragma unroll
      for (int e = 0; e < EE; ++e) a += w3_0e[(e * 23 + k) * 128 + c] * yv[e];
      z3[k] = a;
    }
    float z2[4];
    #pragma unroll
    for (int k = 0; k < 4; ++k) {
      float a = 0.f;
      #pragma unroll
      for (int e = 0; e < EE; ++e) a += w2_0e[(e * 4 + k) * 128 + c] * yv[e];
      z2[k] = a;
    }
    const float* __restrict__ U3base = U3_0e + (size_t)q00 * 368;
    const float* __restrict__ U2base = U2_0e + q00 * 4;
    #pragma unroll 1
    for (int rb = 0; rb < 16; ++rb) {
      float acc[8];
      #pragma unroll
      for (int r = 0; r < 8; ++r) acc[r] = 0.f;
      #pragma unroll 2
      for (int i = 0; i < 16; ++i) {
        const float xi = x_lds[i][lane];
        float pj[23];
        #pragma unroll
        for (int k = 0; k < 23; ++k) pj[k] = xi * z3[k];
        const float* __restrict__ Ur = U3base + (size_t)(rb * 8) * 368 + i * 23;
        #pragma unroll
        for (int r = 0; r < 8; ++r)
          #pragma unroll
          for (int k = 0; k < 23; ++k) acc[r] += Ur[r * 368 + k] * pj[k];
      }
      #pragma unroll
      for (int r = 0; r < 8; ++r) {
        const int q = q00 + rb * 8 + r;
        float a2 = acc[r];
        #pragma unroll
        for (int k = 0; k < 4; ++k) a2 += U2base[(rb * 8 + r) * 4 + k] * z2[k];
        s += a2 * (x_lds[q >> 4][lane] * x_lds[q & 15][lane]);
      }
    }
  }

  red[wv][lane] = s;
  __syncthreads();

  if (tid < 256) {
    const int slot = tid >> 6;
    const int n    = tid & 63;
    const int cc   = ((blk & 1) << 6) + n;
    float u1 = 0.f, z1 = 0.f;
    if (slot < 3) {
      #pragma unroll
      for (int xx = 0; xx < 16; ++xx) u1 += U1_1o[slot * 16 + xx] * x_lds[xx][n];
      #pragma unroll
      for (int e = 0; e < EE; ++e) z1 += w1_1o[e * 128 + cc] * y[b * EE + e];
      out[(size_t)b * 512 + 128 + cc * 3 + slot] = red[2 * slot][n] + red[2 * slot + 1][n] + z1 * u1;
    } else {
      #pragma unroll
      for (int xx = 0; xx < 16; ++xx) u1 += U1_0e[xx] * x_lds[xx][n];
      #pragma unroll
      for (int e = 0; e < EE; ++e) z1 += w1_0e[e * 128 + cc] * y[b * EE + e];
      out[(size_t)b * 512 + cc] = red[6][n] + red[7][n] + z1 * u1;
    }
  }
}

extern "C" void kernel_launch(void* const* d_in, const int* in_sizes, int n_in,
                              void* d_out, int out_size, void* d_ws, size_t ws_size,
                              hipStream_t stream) {
  const float* x     = (const float*)d_in[0];
  const float* y     = (const float*)d_in[1];
  const float* U1_0e = (const float*)d_in[2];
  const float* U2_0e = (const float*)d_in[3];
  const float* U3_0e = (const float*)d_in[4];
  const float* U1_1o = (const float*)d_in[5];
  const float* U2_1o = (const float*)d_in[6];
  const float* U3_1o = (const float*)d_in[7];
  const float* w1_0e = (const float*)d_in[8];
  const float* w2_0e = (const float*)d_in[9];
  const float* w3_0e = (const float*)d_in[10];
  const float* w1_1o = (const float*)d_in[11];
  const float* w2_1o = (const float*)d_in[12];
  const float* w3_1o = (const float*)d_in[13];
  (void)in_sizes; (void)n_in; (void)out_size;

  if (ws_size >= WS_NEED) {
    unsigned short* wsA = (unsigned short*)d_ws;
    unsigned short* wsB = (unsigned short*)((char*)d_ws + WSA_BYTES);
    hipLaunchKernelGGL(prep_kernel, dim3(NB_B + NB_A), dim3(256), 0, stream,
                       x, y, U3_1o, U2_1o, U3_0e, U2_0e,
                       w1_0e, w2_0e, w3_0e, w1_1o, w2_1o, w3_1o,
                       wsA, (unsigned*)wsB);
    hipLaunchKernelGGL(symcon_gemm, dim3(512), dim3(512), 0, stream,
                       x, y, U1_0e, U1_1o, w1_0e, w1_1o,
                       wsA, wsB, (float*)d_out);
  } else {
    hipLaunchKernelGGL(symcon_fallback, dim3(256), dim3(512), 0, stream,
                       x, y, U1_0e, U2_0e, U3_0e, U1_1o, U2_1o, U3_1o,
                       w1_0e, w2_0e, w3_0e, w1_1o, w2_1o, w3_1o,
                       (float*)d_out);
  }
}